// Round 20
// baseline (1553.036 us; speedup 1.0000x reference)
//
#include <hip/hip_runtime.h>
#include <math.h>

#define Tt 128
#define NT 512
#define EPSF 1e-8f

typedef _Float16 f16x2 __attribute__((ext_vector_type(2)));

__device__ __forceinline__ float fsigmoid(float v) { return 1.f / (1.f + expf(-v)); }
__device__ __forceinline__ float fsoftplus(float v) { return (v > 20.f) ? v : log1pf(expf(v)); }
__device__ __forceinline__ float ftanh(float v) { float e = expf(2.f * v); return 1.f - 2.f / (e + 1.f); }

__device__ __forceinline__ float dot2(f16x2 a, f16x2 b, float c) {
#if __has_builtin(__builtin_amdgcn_fdot2)
  return __builtin_amdgcn_fdot2(a, b, c, false);
#else
  return c + (float)a.x * (float)b.x + (float)a.y * (float)b.y;
#endif
}
__device__ __forceinline__ f16x2 pack2(float a, float b) {
  f16x2 p; p.x = (_Float16)a; p.y = (_Float16)b; return p;
}
__device__ __forceinline__ f16x2 bc16(unsigned int v) { return __builtin_bit_cast(f16x2, v); }
__device__ __forceinline__ unsigned int pk2u(float a, float b) {
  return __builtin_bit_cast(unsigned int, pack2(a, b));
}

// ---- DPP reduction primitives ----
template <int C> __device__ __forceinline__ float dppadd(float v) {
  int s = __builtin_amdgcn_update_dpp(0, __builtin_bit_cast(int, v), C, 0xf, 0xf, true);
  return v + __builtin_bit_cast(float, s);
}
template <int C> __device__ __forceinline__ float dppmax(float v) {
  int iv = __builtin_bit_cast(int, v);
  int s = __builtin_amdgcn_update_dpp(iv, iv, C, 0xf, 0xf, false);
  return fmaxf(v, __builtin_bit_cast(float, s));
}
__device__ __forceinline__ float qsum16(float v) {
  v = dppadd<0x111>(v); v = dppadd<0x112>(v); v = dppadd<0x114>(v); v = dppadd<0x118>(v);
  return v;
}
__device__ __forceinline__ float halfsum(float v) {
  v = qsum16(v); v = dppadd<0x142>(v);
  return v;
}
__device__ __forceinline__ float allsum(float v) {
  v = halfsum(v); v = dppadd<0x143>(v);
  return __builtin_bit_cast(float, __builtin_amdgcn_readlane(__builtin_bit_cast(int, v), 63));
}
__device__ __forceinline__ float allmax(float v) {
  v = dppmax<0x111>(v); v = dppmax<0x112>(v); v = dppmax<0x114>(v);
  v = dppmax<0x118>(v); v = dppmax<0x142>(v); v = dppmax<0x143>(v);
  return __builtin_bit_cast(float, __builtin_amdgcn_readlane(__builtin_bit_cast(int, v), 63));
}

// ===== prep: pack big4 [We|Wa|Wk0|Wk1] f32 -> f16x2, column-owner layout =====
__global__ __launch_bounds__(512, 1) void ntm_prep(
    const float* __restrict__ We, const float* __restrict__ Wa,
    const float* __restrict__ Wk, unsigned int* __restrict__ wsb)
{
  const int i = blockIdx.x * 512 + threadIdx.x;   // grid 128*512 = 65536
  const int e = i & 3;
  const int col = (i >> 2) & 511;
  const int q = i >> 11;
  const int k0 = 8 * q + 2 * e;
  const int mat = col >> 7;
  const int mcol = col & 127;
  const float* base = (mat == 0) ? We : (mat == 1) ? Wa : (mat == 2) ? Wk : (Wk + 256 * 128);
  wsb[i] = pk2u(base[k0 * 128 + mcol], base[(k0 + 1) * 128 + mcol]);
}

__global__ __launch_bounds__(NT, 1) void ntm_kernel(
    const float* __restrict__ x, const float* __restrict__ mem0,
    const float* __restrict__ wr0, const float* __restrict__ ww0,
    const float* __restrict__ h0, const float* __restrict__ Wx,
    const float* __restrict__ Wrd, const float* __restrict__ bh,
    const float* __restrict__ bk,
    const float* __restrict__ Wb, const float* __restrict__ bb,
    const float* __restrict__ Wg, const float* __restrict__ bg,
    const float* __restrict__ Ws, const float* __restrict__ bs,
    const float* __restrict__ Wgam, const float* __restrict__ bgam,
    const float* __restrict__ be, const float* __restrict__ ba,
    const uint4* __restrict__ wsb4,
    float* __restrict__ out)
{
  const int b = blockIdx.x;
  const int t = threadIdx.x;
  const int lane = t & 63;
  const int wave = t >> 6;
  const int cg = t & 63;    // matmul column lane (P3)
  const int js = t >> 6;    // inner-dim slice (P3: 8 slices of 32)
  const int c4 = t & 31;    // float4 column group for mem passes
  const int rs = t >> 5;    // row slice for mem passes (16 slices)

  __shared__ __align__(16) float mem[128 * 128];   // 64 KB
  __shared__ __align__(16) uint4 lbigq[4096];      // 64 KB: big4 q-slices 24..31
  __shared__ __align__(16) float part[2048];       // 8 KB
  __shared__ __align__(16) float h_l[256];
  __shared__ __align__(16) unsigned int h16[128];  // h packed f16x2
  __shared__ __align__(16) float xf[128];
  __shared__ __align__(16) float rf[128];
  __shared__ __align__(16) float er[128];
  __shared__ __align__(16) float ad[128];
  __shared__ __align__(16) float kbuf[256];
  __shared__ float wsm_l[3072];
  __shared__ float wr_s[128], ww_s[128];
  __shared__ float normsq[128];
  __shared__ float dotv[256];
  __shared__ float scal[12];
  __shared__ float red2[4];
  __shared__ float bias_big[512];                  // [be | ba | bk0 | bk1]
  __shared__ float bh_l[256];
  __shared__ float bias_sm[12];

  // ===== C-matmul weights resident in regs: 64 f16x2
  f16x2 wcreg[64];
  {
    const float* basep = (js < 4) ? (Wx + (js * 32) * 256) : (Wrd + ((js - 4) * 32) * 256);
    #pragma unroll
    for (int c = 0; c < 4; ++c) {
      const float* bp = basep + c * 64 + cg;
      #pragma unroll
      for (int jj = 0; jj < 16; ++jj) {
        wcreg[c * 16 + jj] = pack2(bp[(2 * jj) * 256], bp[(2 * jj + 1) * 256]);
      }
    }
  }

  // ===== state / bias / small-weight / LDS-weight init =====
  for (int i = t; i < 128 * 128; i += NT) mem[i] = mem0[i];
  for (int i = t; i < 4096; i += NT) lbigq[i] = wsb4[12288 + i];  // q=24..31
  if (t < 128) { wr_s[t] = wr0[b * 128 + t]; ww_s[t] = ww0[b * 128 + t]; }
  if (t < 256) {
    float v = h0[b * 256 + t];
    h_l[t] = v; bh_l[t] = bh[t];
    const float vo = __shfl_xor(v, 1);
    if (!(t & 1)) h16[t >> 1] = pk2u(v, vo);
  }
  bias_big[t] = (t < 128) ? be[t] : (t < 256) ? ba[t - 128] : bk[t - 256];
  for (int i = t; i < 3072; i += NT) {
    const int d = i >> 8, j = i & 255;
    const int head = d / 6, kind = d % 6;
    float v;
    if (kind == 0)      v = Wb[head * 256 + j];
    else if (kind == 1) v = Wg[head * 256 + j];
    else if (kind == 2) v = Wgam[head * 256 + j];
    else                v = Ws[head * 768 + j * 3 + (kind - 3)];
    wsm_l[i] = v;
  }
  if (t < 12) {
    const int head = t / 6, kind = t % 6;
    bias_sm[t] = (kind == 0) ? bb[head] : (kind == 1) ? bg[head]
               : (kind == 2) ? bgam[head] : bs[head * 3 + (kind - 3)];
  }
  __syncthreads();

  const uint4* h16_4 = reinterpret_cast<const uint4*>(h16);

  // q=0..5 prefetch registers (only waves 4-7 use them — for the kbuf columns)
  uint4 pf[6];
  auto issue_pf = [&]() {
    if (wave >= 4) {
      #pragma unroll
      for (int q = 0; q < 6; ++q) pf[q] = wsb4[q * 512 + t];
    }
  };

  // ---- P5': kbuf half (waves 4-7, col t in 256..511) + 12 small dots (t<192)
  auto phase_k = [&]() {
    if (t >= 256) {
      float a0 = 0.f, a1 = 0.f, a2 = 0.f, a3 = 0.f;
      #pragma unroll
      for (int q = 0; q < 32; ++q) {
        uint4 w;
        if (q < 6)        w = pf[q];
        else if (q >= 24) w = lbigq[(q - 24) * 512 + t];
        else              w = wsb4[q * 512 + t];
        const uint4 hq = h16_4[q];
        a0 = dot2(bc16(hq.x), bc16(w.x), a0);
        a1 = dot2(bc16(hq.y), bc16(w.y), a1);
        a2 = dot2(bc16(hq.z), bc16(w.z), a2);
        a3 = dot2(bc16(hq.w), bc16(w.w), a3);
      }
      const float kv = ftanh((a0 + a1) + (a2 + a3) + bias_big[t]);
      kbuf[t - 256] = kv;
      float ks = kv * kv;
      ks = halfsum(ks); ks = dppadd<0x143>(ks);
      if (lane == 63) red2[wave - 4] = ks;
    } else if (t < 192) {
      const int d = t >> 4, l4 = t & 15;
      float s = 0.f;
      #pragma unroll
      for (int q = 0; q < 16; ++q) s += h_l[l4 + 16 * q] * wsm_l[d * 256 + l4 + 16 * q];
      s = qsum16(s);
      if ((lane & 15) == 15) scal[d] = s + bias_sm[d];
    }
  };

  // ---- er/ad half (waves 4-7, col u = t-256), runs concurrent with P7
  auto phase_eradd = [&]() {
    const int u = t - 256;
    float a0 = 0.f, a1 = 0.f, a2 = 0.f, a3 = 0.f;
    #pragma unroll
    for (int q = 0; q < 32; ++q) {
      uint4 w;
      if (q >= 24) w = lbigq[(q - 24) * 512 + u];
      else         w = wsb4[q * 512 + u];
      const uint4 hq = h16_4[q];
      a0 = dot2(bc16(hq.x), bc16(w.x), a0);
      a1 = dot2(bc16(hq.y), bc16(w.y), a1);
      a2 = dot2(bc16(hq.z), bc16(w.z), a2);
      a3 = dot2(bc16(hq.w), bc16(w.w), a3);
    }
    const float acc = (a0 + a1) + (a2 + a3) + bias_big[u];
    if (u < 128) er[u] = fsigmoid(acc);
    else         ad[u - 128] = ftanh(acc);
  };

  // prologue: kbuf/scal then er/ad for step 0 from h0
  issue_pf();
  phase_k();
  __syncthreads();
  if (wave >= 4) phase_eradd();
  __syncthreads();

  for (int step = 0; step < Tt; ++step) {
    // ---- issue kbuf prefetch for this step's P5' (port works during P1-P4)
    issue_pf();

    // ---- P1: x_t -> xf; mem erase/add update; r partials
    if (t < 128) xf[t] = x[((size_t)b * Tt + step) * 128 + t];
    {
      const float4 e4 = *reinterpret_cast<const float4*>(&er[c4 * 4]);
      const float4 a4 = *reinterpret_cast<const float4*>(&ad[c4 * 4]);
      float rx = 0.f, ry = 0.f, rz = 0.f, rw = 0.f;
      #pragma unroll
      for (int k = 0; k < 8; ++k) {
        const int n = rs + 16 * k;
        const float wwn = ww_s[n], wrn = wr_s[n];
        float4 v = *reinterpret_cast<const float4*>(&mem[n * 128 + c4 * 4]);
        v.x = v.x * (1.f - wwn * e4.x) + wwn * a4.x;
        v.y = v.y * (1.f - wwn * e4.y) + wwn * a4.y;
        v.z = v.z * (1.f - wwn * e4.z) + wwn * a4.z;
        v.w = v.w * (1.f - wwn * e4.w) + wwn * a4.w;
        *reinterpret_cast<float4*>(&mem[n * 128 + c4 * 4]) = v;
        rx += wrn * v.x; ry += wrn * v.y; rz += wrn * v.z; rw += wrn * v.w;
      }
      *reinterpret_cast<float4*>(&part[rs * 128 + c4 * 4]) = make_float4(rx, ry, rz, rw);
    }
    __syncthreads();  // b1

    // ---- P2: reduce r partials
    if (t < 128) {
      float r = 0.f;
      #pragma unroll
      for (int s = 0; s < 16; ++s) r += part[s * 128 + t];
      rf[t] = r;
    }
    __syncthreads();  // b2

    // ---- P3: C-matmul partials from [xf|rf] (reg-resident weights)
    {
      const float* src = (js < 4) ? (xf + js * 32) : (rf + (js - 4) * 32);
      float acc[4];
      #pragma unroll
      for (int c = 0; c < 4; ++c) acc[c] = 0.f;
      #pragma unroll
      for (int jj = 0; jj < 16; ++jj) {
        const float2 s2 = *reinterpret_cast<const float2*>(&src[2 * jj]);
        const f16x2 xx = pack2(s2.x, s2.y);
        #pragma unroll
        for (int c = 0; c < 4; ++c) acc[c] = dot2(xx, wcreg[c * 16 + jj], acc[c]);
      }
      #pragma unroll
      for (int c = 0; c < 4; ++c) part[js * 256 + c * 64 + cg] = acc[c];
    }
    __syncthreads();  // b3

    // ---- P4: h = tanh(.); write out; pack h16
    if (t < 256) {
      float v = bh_l[t];
      #pragma unroll
      for (int s = 0; s < 8; ++s) v += part[s * 256 + t];
      v = ftanh(v);
      h_l[t] = v;
      out[((size_t)b * Tt + step) * 256 + t] = v;
      const float vo = __shfl_xor(v, 1);
      if (!(t & 1)) h16[t >> 1] = pk2u(v, vo);
    }
    __syncthreads();  // b4

    // ---- P5': kbuf + k^2 + small dots from new h
    phase_k();
    __syncthreads();  // b5

    // ---- P7 (waves 0-3: both heads' dots + normsq, one mem pass)
    //      || er/ad stream (waves 4-7) — consumed next step's P1
    if (wave < 4) {
      const int cc = t & 31, ns = t >> 5;   // 8 row-slices of 16 rows
      const float4 k40 = *reinterpret_cast<const float4*>(&kbuf[cc * 4]);
      const float4 k41 = *reinterpret_cast<const float4*>(&kbuf[128 + cc * 4]);
      #pragma unroll
      for (int ch = 0; ch < 2; ++ch) {
        float d0[8], d1[8], nq[8];
        #pragma unroll
        for (int ii = 0; ii < 8; ++ii) {
          const int n = ns * 16 + ch * 8 + ii;
          const float4 m4 = *reinterpret_cast<const float4*>(&mem[n * 128 + cc * 4]);
          d0[ii] = k40.x * m4.x + k40.y * m4.y + k40.z * m4.z + k40.w * m4.w;
          d1[ii] = k41.x * m4.x + k41.y * m4.y + k41.z * m4.z + k41.w * m4.w;
          nq[ii] = m4.x * m4.x + m4.y * m4.y + m4.z * m4.z + m4.w * m4.w;
        }
        #pragma unroll
        for (int ii = 0; ii < 8; ++ii) { d0[ii] = halfsum(d0[ii]); d1[ii] = halfsum(d1[ii]); nq[ii] = halfsum(nq[ii]); }
        if ((lane & 31) == 31) {
          #pragma unroll
          for (int ii = 0; ii < 8; ++ii) {
            const int n = ns * 16 + ch * 8 + ii;
            dotv[n] = d0[ii]; dotv[128 + n] = d1[ii]; normsq[n] = nq[ii];
          }
        }
      }
    } else {
      phase_eradd();
    }
    __syncthreads();  // b6

    // ---- P8: addressing tail, wave0=head0, wave1=head1 (DPP all-reduces)
    if (wave < 2) {
      const int head = wave;
      const int h6 = head * 6;
      const float beta  = fsoftplus(scal[h6]);
      const float g     = fsigmoid(scal[h6 + 1]);
      const float gamma = 1.f + fsoftplus(scal[h6 + 2]);
      float e0 = scal[h6 + 3], e1 = scal[h6 + 4], e2 = scal[h6 + 5];
      const float mx3 = fmaxf(e0, fmaxf(e1, e2));
      float x0 = expf(e0 - mx3), x1 = expf(e1 - mx3), x2 = expf(e2 - mx3);
      const float si = 1.f / (x0 + x1 + x2);
      const float s0 = x0 * si, s1 = x1 * si, s2 = x2 * si;
      const float knorm = sqrtf(red2[2 * head] + red2[2 * head + 1]);
      float* wprev = head ? ww_s : wr_s;
      const int n0 = 2 * lane, n1 = 2 * lane + 1;
      float l0 = beta * dotv[head * 128 + n0] / (knorm * sqrtf(normsq[n0]) + EPSF);
      float l1 = beta * dotv[head * 128 + n1] / (knorm * sqrtf(normsq[n1]) + EPSF);
      const float mx = allmax(fmaxf(l0, l1));
      float q0 = expf(l0 - mx), q1 = expf(l1 - mx);
      const float inv = 1.f / allsum(q0 + q1);
      const float wg0 = g * q0 * inv + (1.f - g) * wprev[n0];
      const float wg1 = g * q1 * inv + (1.f - g) * wprev[n1];
      const float wgl = __shfl(wg1, (lane + 63) & 63);
      const float wgr = __shfl(wg0, (lane + 1) & 63);
      const float sh0 = s0 * wgl + s1 * wg0 + s2 * wg1;
      const float sh1 = s0 * wg0 + s1 * wg1 + s2 * wgr;
      const float wp0 = exp2f(gamma * log2f(sh0));
      const float wp1 = exp2f(gamma * log2f(sh1));
      const float itot = 1.f / (allsum(wp0 + wp1) + EPSF);
      wprev[n0] = wp0 * itot;
      wprev[n1] = wp1 * itot;
    }
    __syncthreads();  // b7
  }
}

extern "C" void kernel_launch(void* const* d_in, const int* in_sizes, int n_in,
                              void* d_out, int out_size, void* d_ws, size_t ws_size,
                              hipStream_t stream) {
  const float* x    = (const float*)d_in[0];
  const float* mem0 = (const float*)d_in[1];
  const float* wr0  = (const float*)d_in[2];
  const float* ww0  = (const float*)d_in[3];
  const float* h0   = (const float*)d_in[4];
  const float* Wx   = (const float*)d_in[5];
  const float* Wrd  = (const float*)d_in[6];
  const float* bh   = (const float*)d_in[7];
  const float* Wk   = (const float*)d_in[8];
  const float* bk   = (const float*)d_in[9];
  const float* Wb   = (const float*)d_in[10];
  const float* bb   = (const float*)d_in[11];
  const float* Wg   = (const float*)d_in[12];
  const float* bg   = (const float*)d_in[13];
  const float* Ws   = (const float*)d_in[14];
  const float* bs   = (const float*)d_in[15];
  const float* Wgam = (const float*)d_in[16];
  const float* bgam = (const float*)d_in[17];
  const float* We   = (const float*)d_in[18];
  const float* be   = (const float*)d_in[19];
  const float* Wa   = (const float*)d_in[20];
  const float* ba   = (const float*)d_in[21];
  float* out = (float*)d_out;
  unsigned int* wsb = (unsigned int*)d_ws;   // 65536 uints = 256 KB

  hipLaunchKernelGGL(ntm_prep, dim3(128), dim3(512), 0, stream, We, Wa, Wk, wsb);
  hipLaunchKernelGGL(ntm_kernel, dim3(128), dim3(NT), 0, stream,
                     x, mem0, wr0, ww0, h0, Wx, Wrd, bh, bk, Wb, bb,
                     Wg, bg, Ws, bs, Wgam, bgam, be, ba,
                     (const uint4*)wsb, out);
}

// Round 21
// 806.929 us; speedup vs baseline: 1.9246x; 1.9246x over previous
//
#include <hip/hip_runtime.h>
#include <math.h>

#define Tt 128
#define NT 512
#define EPSF 1e-8f

typedef _Float16 f16x2 __attribute__((ext_vector_type(2)));

__device__ __forceinline__ float fsigmoid(float v) { return 1.f / (1.f + expf(-v)); }
__device__ __forceinline__ float fsoftplus(float v) { return (v > 20.f) ? v : log1pf(expf(v)); }
__device__ __forceinline__ float ftanh(float v) { float e = expf(2.f * v); return 1.f - 2.f / (e + 1.f); }

__device__ __forceinline__ float dot2(f16x2 a, f16x2 b, float c) {
#if __has_builtin(__builtin_amdgcn_fdot2)
  return __builtin_amdgcn_fdot2(a, b, c, false);
#else
  return c + (float)a.x * (float)b.x + (float)a.y * (float)b.y;
#endif
}
__device__ __forceinline__ f16x2 pack2(float a, float b) {
  f16x2 p; p.x = (_Float16)a; p.y = (_Float16)b; return p;
}
__device__ __forceinline__ f16x2 bc16(unsigned int v) { return __builtin_bit_cast(f16x2, v); }
__device__ __forceinline__ unsigned int pk2u(float a, float b) {
  return __builtin_bit_cast(unsigned int, pack2(a, b));
}

// ---- DPP reduction primitives ----
template <int C> __device__ __forceinline__ float dppadd(float v) {
  int s = __builtin_amdgcn_update_dpp(0, __builtin_bit_cast(int, v), C, 0xf, 0xf, true);
  return v + __builtin_bit_cast(float, s);
}
template <int C> __device__ __forceinline__ float dppmax(float v) {
  int iv = __builtin_bit_cast(int, v);
  int s = __builtin_amdgcn_update_dpp(iv, iv, C, 0xf, 0xf, false);
  return fmaxf(v, __builtin_bit_cast(float, s));
}
__device__ __forceinline__ float qsum16(float v) {
  v = dppadd<0x111>(v); v = dppadd<0x112>(v); v = dppadd<0x114>(v); v = dppadd<0x118>(v);
  return v;
}
__device__ __forceinline__ float halfsum(float v) {
  v = qsum16(v); v = dppadd<0x142>(v);
  return v;
}
__device__ __forceinline__ float allsum(float v) {
  v = halfsum(v); v = dppadd<0x143>(v);
  return __builtin_bit_cast(float, __builtin_amdgcn_readlane(__builtin_bit_cast(int, v), 63));
}
__device__ __forceinline__ float allmax(float v) {
  v = dppmax<0x111>(v); v = dppmax<0x112>(v); v = dppmax<0x114>(v);
  v = dppmax<0x118>(v); v = dppmax<0x142>(v); v = dppmax<0x143>(v);
  return __builtin_bit_cast(float, __builtin_amdgcn_readlane(__builtin_bit_cast(int, v), 63));
}

// ===== prep: pack big4 [We|Wa|Wk0|Wk1] f32 -> f16x2, column-owner layout =====
// uint idx i = (q*512 + col)*4 + e ; q=0..31 ; K elems (8q+2e, 8q+2e+1) of column col
// (col>>7 selects matrix, col&127 its column)
__global__ __launch_bounds__(512, 1) void ntm_prep(
    const float* __restrict__ We, const float* __restrict__ Wa,
    const float* __restrict__ Wk, unsigned int* __restrict__ wsb)
{
  const int i = blockIdx.x * 512 + threadIdx.x;   // grid 128*512 = 65536
  const int e = i & 3;
  const int col = (i >> 2) & 511;
  const int q = i >> 11;
  const int k0 = 8 * q + 2 * e;
  const int mat = col >> 7;
  const int mcol = col & 127;
  const float* base = (mat == 0) ? We : (mat == 1) ? Wa : (mat == 2) ? Wk : (Wk + 256 * 128);
  wsb[i] = pk2u(base[k0 * 128 + mcol], base[(k0 + 1) * 128 + mcol]);
}

__global__ __launch_bounds__(NT, 1) void ntm_kernel(
    const float* __restrict__ x, const float* __restrict__ mem0,
    const float* __restrict__ wr0, const float* __restrict__ ww0,
    const float* __restrict__ h0, const float* __restrict__ Wx,
    const float* __restrict__ Wrd, const float* __restrict__ bh,
    const float* __restrict__ bk,
    const float* __restrict__ Wb, const float* __restrict__ bb,
    const float* __restrict__ Wg, const float* __restrict__ bg,
    const float* __restrict__ Ws, const float* __restrict__ bs,
    const float* __restrict__ Wgam, const float* __restrict__ bgam,
    const float* __restrict__ be, const float* __restrict__ ba,
    const uint4* __restrict__ wsb4,
    float* __restrict__ out)
{
  const int b = blockIdx.x;
  const int t = threadIdx.x;
  const int lane = t & 63;
  const int wave = t >> 6;
  const int cg = t & 63;    // matmul column lane (P3)
  const int js = t >> 6;    // inner-dim slice (P3: 8 slices of 32)
  const int c4 = t & 31;    // float4 column group for mem passes
  const int rs = t >> 5;    // row slice for mem passes (16 slices)

  __shared__ __align__(16) float mem[128 * 128];   // 64 KB
  __shared__ __align__(16) uint4 lbigq[3584];      // 56 KB: big4 q-slices 25..31
  __shared__ __align__(16) float part[2048];       // 8 KB
  __shared__ __align__(16) float h_l[256];
  __shared__ __align__(16) unsigned int h16[128];  // h packed f16x2
  __shared__ __align__(16) float xf[128];
  __shared__ __align__(16) float rf[128];
  __shared__ __align__(16) float er[128];
  __shared__ __align__(16) float ad[128];
  __shared__ __align__(16) float kbuf[256];
  __shared__ float wsm_l[3072];
  __shared__ float wr_s[128], ww_s[128];
  __shared__ float normsq[128];
  __shared__ float dotv[256];
  __shared__ float scal[12];
  __shared__ float red2[4];
  __shared__ float bias_big[512];                  // [be | ba | bk0 | bk1]
  __shared__ float bh_l[256];
  __shared__ float bias_sm[12];

  // ===== C-matmul weights resident in regs: 64 f16x2
  f16x2 wcreg[64];
  {
    const float* basep = (js < 4) ? (Wx + (js * 32) * 256) : (Wrd + ((js - 4) * 32) * 256);
    #pragma unroll
    for (int c = 0; c < 4; ++c) {
      const float* bp = basep + c * 64 + cg;
      #pragma unroll
      for (int jj = 0; jj < 16; ++jj) {
        wcreg[c * 16 + jj] = pack2(bp[(2 * jj) * 256], bp[(2 * jj + 1) * 256]);
      }
    }
  }

  // ===== state / bias / small-weight / LDS-weight init =====
  for (int i = t; i < 128 * 128; i += NT) mem[i] = mem0[i];
  for (int i = t; i < 3584; i += NT) lbigq[i] = wsb4[12800 + i];  // q=25..31
  if (t < 128) { wr_s[t] = wr0[b * 128 + t]; ww_s[t] = ww0[b * 128 + t]; }
  if (t < 256) {
    float v = h0[b * 256 + t];
    h_l[t] = v; bh_l[t] = bh[t];
    const float vo = __shfl_xor(v, 1);
    if (!(t & 1)) h16[t >> 1] = pk2u(v, vo);
  }
  bias_big[t] = (t < 128) ? be[t] : (t < 256) ? ba[t - 128] : bk[t - 256];
  for (int i = t; i < 3072; i += NT) {
    const int d = i >> 8, j = i & 255;
    const int head = d / 6, kind = d % 6;
    float v;
    if (kind == 0)      v = Wb[head * 256 + j];
    else if (kind == 1) v = Wg[head * 256 + j];
    else if (kind == 2) v = Wgam[head * 256 + j];
    else                v = Ws[head * 768 + j * 3 + (kind - 3)];
    wsm_l[i] = v;
  }
  if (t < 12) {
    const int head = t / 6, kind = t % 6;
    bias_sm[t] = (kind == 0) ? bb[head] : (kind == 1) ? bg[head]
               : (kind == 2) ? bgam[head] : bs[head * 3 + (kind - 3)];
  }
  __syncthreads();

  const uint4* h16_4 = reinterpret_cast<const uint4*>(h16);

  // q=0..3 prefetch registers (issued early, consumed in P5)
  uint4 pf[4];
  auto issue_pf = [&]() {
    #pragma unroll
    for (int q = 0; q < 4; ++q) pf[q] = wsb4[q * 512 + t];
  };

  // ---- P5 fused: column-owner big4 (thread t = output col t) -> er/ad/kbuf
  //      + k^2 DPP + 12 small dots. No partials, no extra barrier.
  auto phase_big4 = [&]() {
    float a0 = 0.f, a1 = 0.f, a2 = 0.f, a3 = 0.f;
    #pragma unroll
    for (int q = 0; q < 32; ++q) {
      uint4 w;
      if (q < 4)        w = pf[q];
      else if (q >= 25) w = lbigq[(q - 25) * 512 + t];
      else              w = wsb4[q * 512 + t];
      const uint4 hq = h16_4[q];        // wave-uniform -> LDS broadcast
      a0 = dot2(bc16(hq.x), bc16(w.x), a0);
      a1 = dot2(bc16(hq.y), bc16(w.y), a1);
      a2 = dot2(bc16(hq.z), bc16(w.z), a2);
      a3 = dot2(bc16(hq.w), bc16(w.w), a3);
    }
    const float acc = (a0 + a1) + (a2 + a3) + bias_big[t];
    if (t < 128)      er[t] = fsigmoid(acc);
    else if (t < 256) ad[t - 128] = ftanh(acc);
    else {
      const float kv = ftanh(acc);
      kbuf[t - 256] = kv;
      float ks = kv * kv;
      ks = halfsum(ks); ks = dppadd<0x143>(ks);
      if (lane == 63) red2[wave - 4] = ks;
    }
    if (t < 384) {
      const int d = t >> 5, l5 = t & 31;
      float s = 0.f;
      #pragma unroll
      for (int q = 0; q < 8; ++q) s += h_l[l5 + 32 * q] * wsm_l[d * 256 + l5 + 32 * q];
      s = halfsum(s);
      if ((lane & 31) == 31) scal[d] = s + bias_sm[d];
    }
  };

  // prologue: er/ad/k/scal for step 0 from h0
  issue_pf();
  phase_big4();
  __syncthreads();

  for (int step = 0; step < Tt; ++step) {
    // ---- issue q=0..3 prefetch for this step's P5 (port works during P1-P4)
    issue_pf();

    // ---- P1: x_t -> xf; mem erase/add update; r partials
    if (t < 128) xf[t] = x[((size_t)b * Tt + step) * 128 + t];
    {
      const float4 e4 = *reinterpret_cast<const float4*>(&er[c4 * 4]);
      const float4 a4 = *reinterpret_cast<const float4*>(&ad[c4 * 4]);
      float rx = 0.f, ry = 0.f, rz = 0.f, rw = 0.f;
      #pragma unroll
      for (int k = 0; k < 8; ++k) {
        const int n = rs + 16 * k;
        const float wwn = ww_s[n], wrn = wr_s[n];
        float4 v = *reinterpret_cast<const float4*>(&mem[n * 128 + c4 * 4]);
        v.x = v.x * (1.f - wwn * e4.x) + wwn * a4.x;
        v.y = v.y * (1.f - wwn * e4.y) + wwn * a4.y;
        v.z = v.z * (1.f - wwn * e4.z) + wwn * a4.z;
        v.w = v.w * (1.f - wwn * e4.w) + wwn * a4.w;
        *reinterpret_cast<float4*>(&mem[n * 128 + c4 * 4]) = v;
        rx += wrn * v.x; ry += wrn * v.y; rz += wrn * v.z; rw += wrn * v.w;
      }
      *reinterpret_cast<float4*>(&part[rs * 128 + c4 * 4]) = make_float4(rx, ry, rz, rw);
    }
    __syncthreads();  // b1

    // ---- P2: reduce r partials
    if (t < 128) {
      float r = 0.f;
      #pragma unroll
      for (int s = 0; s < 16; ++s) r += part[s * 128 + t];
      rf[t] = r;
    }
    __syncthreads();  // b2

    // ---- P3: C-matmul partials from [xf|rf] (reg-resident weights)
    {
      const float* src = (js < 4) ? (xf + js * 32) : (rf + (js - 4) * 32);
      float acc[4];
      #pragma unroll
      for (int c = 0; c < 4; ++c) acc[c] = 0.f;
      #pragma unroll
      for (int jj = 0; jj < 16; ++jj) {
        const float2 s2 = *reinterpret_cast<const float2*>(&src[2 * jj]);
        const f16x2 xx = pack2(s2.x, s2.y);
        #pragma unroll
        for (int c = 0; c < 4; ++c) acc[c] = dot2(xx, wcreg[c * 16 + jj], acc[c]);
      }
      #pragma unroll
      for (int c = 0; c < 4; ++c) part[js * 256 + c * 64 + cg] = acc[c];
    }
    __syncthreads();  // b3

    // ---- P4: h = tanh(.); write out; pack h16
    if (t < 256) {
      float v = bh_l[t];
      #pragma unroll
      for (int s = 0; s < 8; ++s) v += part[s * 256 + t];
      v = ftanh(v);
      h_l[t] = v;
      out[((size_t)b * Tt + step) * 256 + t] = v;
      const float vo = __shfl_xor(v, 1);
      if (!(t & 1)) h16[t >> 1] = pk2u(v, vo);
    }
    __syncthreads();  // b4

    // ---- P5: fused column-owner big4 + k^2 + small dots from new h
    phase_big4();
    __syncthreads();  // b5

    // ---- P7: content dots + row normsq fused (DPP half-reduction)
    {
      const int head = t >> 8;           // waves 0-3: head0, 4-7: head1
      const int u = t & 255;
      const int cc = u & 31, ns = u >> 5; // half-wave owns 16 rows
      const float4 k4 = *reinterpret_cast<const float4*>(&kbuf[head * 128 + cc * 4]);
      #pragma unroll
      for (int ch = 0; ch < 2; ++ch) {
        float dsum[8], qsum[8];
        #pragma unroll
        for (int ii = 0; ii < 8; ++ii) {
          const int n = ns * 16 + ch * 8 + ii;
          const float4 m4 = *reinterpret_cast<const float4*>(&mem[n * 128 + cc * 4]);
          dsum[ii] = k4.x * m4.x + k4.y * m4.y + k4.z * m4.z + k4.w * m4.w;
          qsum[ii] = m4.x * m4.x + m4.y * m4.y + m4.z * m4.z + m4.w * m4.w;
        }
        #pragma unroll
        for (int ii = 0; ii < 8; ++ii) dsum[ii] = halfsum(dsum[ii]);
        if (head == 0) {
          #pragma unroll
          for (int ii = 0; ii < 8; ++ii) qsum[ii] = halfsum(qsum[ii]);
        }
        if ((lane & 31) == 31) {
          #pragma unroll
          for (int ii = 0; ii < 8; ++ii) dotv[head * 128 + ns * 16 + ch * 8 + ii] = dsum[ii];
          if (head == 0) {
            #pragma unroll
            for (int ii = 0; ii < 8; ++ii) normsq[ns * 16 + ch * 8 + ii] = qsum[ii];
          }
        }
      }
    }
    __syncthreads();  // b6

    // ---- P8: addressing tail, wave0=head0, wave1=head1 (DPP all-reduces)
    if (wave < 2) {
      const int head = wave;
      const int h6 = head * 6;
      const float beta  = fsoftplus(scal[h6]);
      const float g     = fsigmoid(scal[h6 + 1]);
      const float gamma = 1.f + fsoftplus(scal[h6 + 2]);
      float e0 = scal[h6 + 3], e1 = scal[h6 + 4], e2 = scal[h6 + 5];
      const float mx3 = fmaxf(e0, fmaxf(e1, e2));
      float x0 = expf(e0 - mx3), x1 = expf(e1 - mx3), x2 = expf(e2 - mx3);
      const float si = 1.f / (x0 + x1 + x2);
      const float s0 = x0 * si, s1 = x1 * si, s2 = x2 * si;
      const float knorm = sqrtf(red2[2 * head] + red2[2 * head + 1]);
      float* wprev = head ? ww_s : wr_s;
      const int n0 = 2 * lane, n1 = 2 * lane + 1;
      float l0 = beta * dotv[head * 128 + n0] / (knorm * sqrtf(normsq[n0]) + EPSF);
      float l1 = beta * dotv[head * 128 + n1] / (knorm * sqrtf(normsq[n1]) + EPSF);
      const float mx = allmax(fmaxf(l0, l1));
      float q0 = expf(l0 - mx), q1 = expf(l1 - mx);
      const float inv = 1.f / allsum(q0 + q1);
      const float wg0 = g * q0 * inv + (1.f - g) * wprev[n0];
      const float wg1 = g * q1 * inv + (1.f - g) * wprev[n1];
      const float wgl = __shfl(wg1, (lane + 63) & 63);
      const float wgr = __shfl(wg0, (lane + 1) & 63);
      const float sh0 = s0 * wgl + s1 * wg0 + s2 * wg1;
      const float sh1 = s0 * wg0 + s1 * wg1 + s2 * wgr;
      const float wp0 = exp2f(gamma * log2f(sh0));
      const float wp1 = exp2f(gamma * log2f(sh1));
      const float itot = 1.f / (allsum(wp0 + wp1) + EPSF);
      wprev[n0] = wp0 * itot;
      wprev[n1] = wp1 * itot;
    }
    __syncthreads();  // b7
  }
}

extern "C" void kernel_launch(void* const* d_in, const int* in_sizes, int n_in,
                              void* d_out, int out_size, void* d_ws, size_t ws_size,
                              hipStream_t stream) {
  const float* x    = (const float*)d_in[0];
  const float* mem0 = (const float*)d_in[1];
  const float* wr0  = (const float*)d_in[2];
  const float* ww0  = (const float*)d_in[3];
  const float* h0   = (const float*)d_in[4];
  const float* Wx   = (const float*)d_in[5];
  const float* Wrd  = (const float*)d_in[6];
  const float* bh   = (const float*)d_in[7];
  const float* Wk   = (const float*)d_in[8];
  const float* bk   = (const float*)d_in[9];
  const float* Wb   = (const float*)d_in[10];
  const float* bb   = (const float*)d_in[11];
  const float* Wg   = (const float*)d_in[12];
  const float* bg   = (const float*)d_in[13];
  const float* Ws   = (const float*)d_in[14];
  const float* bs   = (const float*)d_in[15];
  const float* Wgam = (const float*)d_in[16];
  const float* bgam = (const float*)d_in[17];
  const float* We   = (const float*)d_in[18];
  const float* be   = (const float*)d_in[19];
  const float* Wa   = (const float*)d_in[20];
  const float* ba   = (const float*)d_in[21];
  float* out = (float*)d_out;
  unsigned int* wsb = (unsigned int*)d_ws;   // 65536 uints = 256 KB

  hipLaunchKernelGGL(ntm_prep, dim3(128), dim3(512), 0, stream, We, Wa, Wk, wsb);
  hipLaunchKernelGGL(ntm_kernel, dim3(128), dim3(NT), 0, stream,
                     x, mem0, wr0, ww0, h0, Wx, Wrd, bh, bk, Wb, bb,
                     Wg, bg, Ws, bs, Wgam, bgam, be, ba,
                     (const uint4*)wsb, out);
}